// Round 1
// baseline (46.471 us; speedup 1.0000x reference)
//
#include <hip/hip_runtime.h>
#include <hip/hip_bf16.h>

#define ALPHA 0.2f
constexpr int B = 8, K = 256, F = 64, E = 128;   // E = 2*F

// ---------------------------------------------------------------------------
// k1: per (b,k) row of x, compute
//   u[b,k,e]  = dot(x[b,k,:], lin_w[e, 0:F])  + lin_b[e]      (layout [b][k][e])
//   v[b,k,e]  = dot(x[b,k,:], lin_w[e, F:2F])                 (layout [b][e/4][k][4])
// 2048 blocks x 128 threads (one thread per e).
// ---------------------------------------------------------------------------
__global__ __launch_bounds__(128) void gat_k1(
    const float* __restrict__ x, const float* __restrict__ lin_w,
    const float* __restrict__ lin_b,
    float* __restrict__ u, float* __restrict__ vT4)
{
    const int bk = blockIdx.x;          // 0..B*K-1
    const int b  = bk >> 8;             // K == 256
    const int k  = bk & (K - 1);
    const int e  = threadIdx.x;         // 0..E-1

    __shared__ float xs[F];
    if (e < F) xs[e] = x[bk * F + e];
    __syncthreads();

    const float* w = lin_w + e * (2 * F);
    float acc1 = 0.f, acc2 = 0.f;
#pragma unroll
    for (int f = 0; f < F; f += 4) {
        float4 xv  = *(const float4*)&xs[f];
        float4 w1v = *(const float4*)&w[f];
        float4 w2v = *(const float4*)&w[F + f];
        acc1 = fmaf(xv.x, w1v.x, acc1); acc1 = fmaf(xv.y, w1v.y, acc1);
        acc1 = fmaf(xv.z, w1v.z, acc1); acc1 = fmaf(xv.w, w1v.w, acc1);
        acc2 = fmaf(xv.x, w2v.x, acc2); acc2 = fmaf(xv.y, w2v.y, acc2);
        acc2 = fmaf(xv.z, w2v.z, acc2); acc2 = fmaf(xv.w, w2v.w, acc2);
    }
    u[bk * E + e] = acc1 + lin_b[e];
    const int e4 = e >> 2, c = e & 3;
    vT4[(((b * (E / 4) + e4) * K) + k) * 4 + c] = acc2;
}

// ---------------------------------------------------------------------------
// k2: one block per (b,i); thread t owns column j = t.
//   e_j = sum_e a[e]*lrelu(u[b,i,e] + v[b,j,e]) + att_bias[i,j]
//   p   = softmax_j(e)
//   h_f = sigmoid(sum_j p_j * x[b,j,f])
//   out[b,i,o] = sum_f h_f * fc_w[o,f] + fc_b[o]
// ---------------------------------------------------------------------------
__global__ __launch_bounds__(256) void gat_k2(
    const float* __restrict__ x, const float* __restrict__ a,
    const float* __restrict__ att_bias, const float* __restrict__ fc_w,
    const float* __restrict__ fc_b, const float* __restrict__ u,
    const float* __restrict__ vT4, float* __restrict__ out)
{
    const int bi = blockIdx.x;          // 0..B*K-1
    const int b  = bi >> 8;
    const int i  = bi & (K - 1);
    const int t  = threadIdx.x;         // 0..255 == column j

    __shared__ float us[E];
    __shared__ float a1s[E];
    __shared__ float a2s[E];
    __shared__ float p[K];
    __shared__ float red[8];
    __shared__ float hpart[4][F];
    __shared__ float h[F];

    if (t < E) {
        us[t]  = u[bi * E + t];
        float av = a[t];
        a1s[t] = av;
        a2s[t] = av * ALPHA;
    }
    __syncthreads();

    // ---- e_j: contraction over E, float4-vectorized & coalesced ----
    const float4* v4 = (const float4*)vT4 + (size_t)b * (E / 4) * K + t;
    float ej = 0.f;
#pragma unroll 8
    for (int e4 = 0; e4 < E / 4; ++e4) {
        float4 v  = v4[e4 * K];
        float4 uu = *(const float4*)&us[e4 * 4];
        float4 m1 = *(const float4*)&a1s[e4 * 4];
        float4 m2 = *(const float4*)&a2s[e4 * 4];
        float tx = uu.x + v.x; ej = fmaf(tx >= 0.f ? m1.x : m2.x, tx, ej);
        float ty = uu.y + v.y; ej = fmaf(ty >= 0.f ? m1.y : m2.y, ty, ej);
        float tz = uu.z + v.z; ej = fmaf(tz >= 0.f ? m1.z : m2.z, tz, ej);
        float tw = uu.w + v.w; ej = fmaf(tw >= 0.f ? m1.w : m2.w, tw, ej);
    }
    ej += att_bias[i * K + t];

    // ---- softmax over the 256 threads ----
    const int wave = t >> 6, lane = t & 63;
    float m = ej;
#pragma unroll
    for (int off = 32; off >= 1; off >>= 1) m = fmaxf(m, __shfl_xor(m, off));
    if (lane == 0) red[wave] = m;
    __syncthreads();
    const float mall = fmaxf(fmaxf(red[0], red[1]), fmaxf(red[2], red[3]));
    const float ex = __expf(ej - mall);
    float s = ex;
#pragma unroll
    for (int off = 32; off >= 1; off >>= 1) s += __shfl_xor(s, off);
    if (lane == 0) red[4 + wave] = s;
    __syncthreads();
    const float stot = red[4] + red[5] + red[6] + red[7];
    p[t] = ex / stot;
    __syncthreads();

    // ---- h_f = sigmoid(sum_j p_j * x[b,j,f]); 4 j-quarters in parallel ----
    const int f = t & (F - 1), q = t >> 6;
    const float* xb = x + (size_t)b * K * F;
    float hacc = 0.f;
#pragma unroll 4
    for (int jj = 0; jj < 64; ++jj) {
        int j = q * 64 + jj;
        hacc = fmaf(p[j], xb[j * F + f], hacc);
    }
    hpart[q][f] = hacc;
    __syncthreads();
    if (t < F) {
        float hv = hpart[0][t] + hpart[1][t] + hpart[2][t] + hpart[3][t];
        h[t] = 1.f / (1.f + __expf(-hv));
    }
    __syncthreads();

    // ---- out[b,i,o] = h . fc_w[o,:] + fc_b[o] ----
    if (t < F) {
        const int o = t;
        const float* wrow = fc_w + o * F;
        float acc = 0.f;
#pragma unroll
        for (int ff = 0; ff < F; ff += 4) {
            float4 hv = *(const float4*)&h[ff];
            float4 wv = *(const float4*)&wrow[ff];
            acc = fmaf(hv.x, wv.x, acc); acc = fmaf(hv.y, wv.y, acc);
            acc = fmaf(hv.z, wv.z, acc); acc = fmaf(hv.w, wv.w, acc);
        }
        out[bi * F + o] = acc + fc_b[o];
    }
}

extern "C" void kernel_launch(void* const* d_in, const int* in_sizes, int n_in,
                              void* d_out, int out_size, void* d_ws, size_t ws_size,
                              hipStream_t stream) {
    const float* x        = (const float*)d_in[0];
    const float* lin_w    = (const float*)d_in[1];
    const float* lin_b    = (const float*)d_in[2];
    const float* a        = (const float*)d_in[3];
    const float* att_bias = (const float*)d_in[4];
    const float* fc_w     = (const float*)d_in[5];
    const float* fc_b     = (const float*)d_in[6];
    float* out = (float*)d_out;

    float* u   = (float*)d_ws;                       // B*K*E floats = 1 MiB
    float* vT4 = u + (size_t)B * K * E;              // B*K*E floats = 1 MiB

    gat_k1<<<B * K, 128, 0, stream>>>(x, lin_w, lin_b, u, vT4);
    gat_k2<<<B * K, 256, 0, stream>>>(x, a, att_bias, fc_w, fc_b, u, vT4, out);
}

// Round 2
// 34.241 us; speedup vs baseline: 1.3572x; 1.3572x over previous
//
#include <hip/hip_runtime.h>
#include <hip/hip_bf16.h>

#define ALPHA 0.2f
constexpr int B = 8, K = 256, F = 64, E = 128;   // E = 2*F

// ---------------------------------------------------------------------------
// Workspace layout (floats):
//   u   [B*K][E]                          262144
//   vT  float4-transposed v: f4-index (b*32+e4)*K + k, component e&3   262144
//   c   [B*K]  = sum_e a_e * v[bk][e]       2048
//   d   [B*K]  = sum_e a_e * u[bk][e]       2048
//   wq  float4 [32][128]: {w1[e][2f],w1[e][2f+1],w2[e][2f],w2[e][2f+1]} 16384
//   fcp float4 [16][64] : {fc_w[o][4f..4f+3]} transposed-packed          4096
// ---------------------------------------------------------------------------

// k0: pack weights for coalesced access (20 blocks x 256)
__global__ __launch_bounds__(256) void gat_k0(
    const float* __restrict__ lin_w, const float* __restrict__ fc_w,
    float4* __restrict__ wq, float4* __restrict__ fcp)
{
    int idx = blockIdx.x * 256 + threadIdx.x;
    if (idx < 32 * E) {                       // 4096: lin_w pack
        int e = idx & (E - 1), f2 = idx >> 7;
        const float* r = lin_w + e * (2 * F) + 2 * f2;
        wq[f2 * E + e] = make_float4(r[0], r[1], r[F], r[F + 1]);
    } else {                                  // 1024: fc_w pack
        int k = idx - 32 * E;
        int f4 = k >> 6, o = k & 63;
        const float* r = fc_w + o * F + f4 * 4;
        fcp[k] = make_float4(r[0], r[1], r[2], r[3]);
    }
}

// k1: 512 blocks x 128 threads; thread e computes rows row0..row0+3.
__global__ __launch_bounds__(128) void gat_k1(
    const float* __restrict__ x, const float4* __restrict__ wq,
    const float* __restrict__ lin_b, const float* __restrict__ a,
    float* __restrict__ u, float* __restrict__ vT,
    float* __restrict__ c, float* __restrict__ d)
{
    const int e = threadIdx.x;               // 0..127
    const int row0 = blockIdx.x * 4;

    __shared__ float xs[4 * F];              // 4 rows of x
    xs[e] = x[row0 * F + e];
    xs[e + 128] = x[row0 * F + e + 128];
    __syncthreads();

    float acc1[4] = {0, 0, 0, 0}, acc2[4] = {0, 0, 0, 0};
#pragma unroll
    for (int f2 = 0; f2 < 32; ++f2) {
        float4 w = wq[f2 * E + e];           // coalesced 16B/lane
#pragma unroll
        for (int r = 0; r < 4; ++r) {
            float xa = xs[r * F + 2 * f2], xb = xs[r * F + 2 * f2 + 1];
            acc1[r] = fmaf(w.x, xa, fmaf(w.y, xb, acc1[r]));
            acc2[r] = fmaf(w.z, xa, fmaf(w.w, xb, acc2[r]));
        }
    }

    const float bb = lin_b[e], av = a[e];
    float vals[8];
#pragma unroll
    for (int r = 0; r < 4; ++r) {
        int bk = row0 + r;
        float uu = acc1[r] + bb;
        u[bk * E + e] = uu;
        int b = bk >> 8, k = bk & 255;
        vT[(((b * 32) + (e >> 2)) * K + k) * 4 + (e & 3)] = acc2[r];
        vals[r]     = av * acc2[r];          // c partial
        vals[4 + r] = av * uu;               // d partial
    }
#pragma unroll
    for (int off = 32; off; off >>= 1)
#pragma unroll
        for (int q = 0; q < 8; ++q) vals[q] += __shfl_xor(vals[q], off);

    __shared__ float red[2][8];
    const int wave = e >> 6, lane = e & 63;
    if (lane == 0)
#pragma unroll
        for (int q = 0; q < 8; ++q) red[wave][q] = vals[q];
    __syncthreads();
    if (e < 4)      c[row0 + e] = red[0][e] + red[1][e];
    else if (e < 8) d[row0 + e - 4] = red[0][e] + red[1][e];
}

// k2: 512 blocks x 256 threads; block = (b, 4 consecutive i rows); thread t = j.
__global__ __launch_bounds__(256) void gat_k2(
    const float* __restrict__ x, const float* __restrict__ a,
    const float* __restrict__ att_bias, const float4* __restrict__ fcp,
    const float* __restrict__ fc_b, const float* __restrict__ u,
    const float4* __restrict__ vT4, const float* __restrict__ c,
    const float* __restrict__ d, float* __restrict__ out)
{
    const int blk = blockIdx.x;
    const int b = blk >> 6;
    const int i0 = (blk & 63) * 4;
    const int t = threadIdx.x;               // j
    const int wave = t >> 6, lane = t & 63;

    __shared__ float ps[4 * 257];            // padded: bank-conflict-free
    __shared__ float4 hpart[4][4][16];
    __shared__ float4 h4s[4][16];
    __shared__ float redm[4][4], reds[4][4];

    const float cj = c[b * K + t];

    // ---- e-loop: ej_abs[i] = sum_e a_e * |u_ie + v_je|  (2 VALU/elem) ----
    const float4* v4  = vT4 + (size_t)b * 32 * K + t;
    const float4* ub4 = (const float4*)u + (size_t)(b * K + i0) * 32;  // uniform
    const float4* a4  = (const float4*)a;                               // uniform
    float ej0 = 0.f, ej1 = 0.f, ej2 = 0.f, ej3 = 0.f;
#pragma unroll 8
    for (int e4 = 0; e4 < 32; ++e4) {
        float4 v  = v4[e4 * K];              // coalesced 16B/lane
        float4 aa = a4[e4];
        float4 u0 = ub4[e4], u1 = ub4[32 + e4], u2 = ub4[64 + e4], u3 = ub4[96 + e4];
        ej0 = fmaf(aa.x, fabsf(u0.x + v.x), ej0); ej0 = fmaf(aa.y, fabsf(u0.y + v.y), ej0);
        ej0 = fmaf(aa.z, fabsf(u0.z + v.z), ej0); ej0 = fmaf(aa.w, fabsf(u0.w + v.w), ej0);
        ej1 = fmaf(aa.x, fabsf(u1.x + v.x), ej1); ej1 = fmaf(aa.y, fabsf(u1.y + v.y), ej1);
        ej1 = fmaf(aa.z, fabsf(u1.z + v.z), ej1); ej1 = fmaf(aa.w, fabsf(u1.w + v.w), ej1);
        ej2 = fmaf(aa.x, fabsf(u2.x + v.x), ej2); ej2 = fmaf(aa.y, fabsf(u2.y + v.y), ej2);
        ej2 = fmaf(aa.z, fabsf(u2.z + v.z), ej2); ej2 = fmaf(aa.w, fabsf(u2.w + v.w), ej2);
        ej3 = fmaf(aa.x, fabsf(u3.x + v.x), ej3); ej3 = fmaf(aa.y, fabsf(u3.y + v.y), ej3);
        ej3 = fmaf(aa.z, fabsf(u3.z + v.z), ej3); ej3 = fmaf(aa.w, fabsf(u3.w + v.w), ej3);
    }
    // e_ij = 0.6(d_i + c_j) + 0.4*ej_abs + att_bias   (lrelu = 0.6 z + 0.4|z|)
    const float d0 = d[b * K + i0], d1 = d[b * K + i0 + 1];
    const float d2 = d[b * K + i0 + 2], d3 = d[b * K + i0 + 3];
    float e0 = fmaf(0.6f, d0 + cj, 0.4f * ej0) + att_bias[(i0 + 0) * K + t];
    float e1 = fmaf(0.6f, d1 + cj, 0.4f * ej1) + att_bias[(i0 + 1) * K + t];
    float e2 = fmaf(0.6f, d2 + cj, 0.4f * ej2) + att_bias[(i0 + 2) * K + t];
    float e3 = fmaf(0.6f, d3 + cj, 0.4f * ej3) + att_bias[(i0 + 3) * K + t];

    // ---- softmax over j (4 rows) ----
    float m0 = e0, m1 = e1, m2 = e2, m3 = e3;
#pragma unroll
    for (int off = 32; off; off >>= 1) {
        m0 = fmaxf(m0, __shfl_xor(m0, off)); m1 = fmaxf(m1, __shfl_xor(m1, off));
        m2 = fmaxf(m2, __shfl_xor(m2, off)); m3 = fmaxf(m3, __shfl_xor(m3, off));
    }
    if (lane == 0) { redm[wave][0] = m0; redm[wave][1] = m1; redm[wave][2] = m2; redm[wave][3] = m3; }
    __syncthreads();
    m0 = fmaxf(fmaxf(redm[0][0], redm[1][0]), fmaxf(redm[2][0], redm[3][0]));
    m1 = fmaxf(fmaxf(redm[0][1], redm[1][1]), fmaxf(redm[2][1], redm[3][1]));
    m2 = fmaxf(fmaxf(redm[0][2], redm[1][2]), fmaxf(redm[2][2], redm[3][2]));
    m3 = fmaxf(fmaxf(redm[0][3], redm[1][3]), fmaxf(redm[2][3], redm[3][3]));
    float x0 = __expf(e0 - m0), x1 = __expf(e1 - m1), x2 = __expf(e2 - m2), x3 = __expf(e3 - m3);
    float s0 = x0, s1 = x1, s2 = x2, s3 = x3;
#pragma unroll
    for (int off = 32; off; off >>= 1) {
        s0 += __shfl_xor(s0, off); s1 += __shfl_xor(s1, off);
        s2 += __shfl_xor(s2, off); s3 += __shfl_xor(s3, off);
    }
    if (lane == 0) { reds[wave][0] = s0; reds[wave][1] = s1; reds[wave][2] = s2; reds[wave][3] = s3; }
    __syncthreads();
    s0 = reds[0][0] + reds[1][0] + reds[2][0] + reds[3][0];
    s1 = reds[0][1] + reds[1][1] + reds[2][1] + reds[3][1];
    s2 = reds[0][2] + reds[1][2] + reds[2][2] + reds[3][2];
    s3 = reds[0][3] + reds[1][3] + reds[2][3] + reds[3][3];
    ps[0 * 257 + t] = x0 / s0;
    ps[1 * 257 + t] = x1 / s1;
    ps[2 * 257 + t] = x2 / s2;
    ps[3 * 257 + t] = x3 / s3;
    __syncthreads();

    // ---- h[i,f] = sigmoid(sum_j p[i,j] x[b,j,f]) ; thread = (jq, il, fq) ----
    {
        const int jq = wave, il = (t >> 4) & 3, fq = t & 15;
        const float4* xb4 = (const float4*)x + (size_t)b * K * 16;
        float4 hacc = make_float4(0.f, 0.f, 0.f, 0.f);
#pragma unroll 8
        for (int jj = 0; jj < 64; ++jj) {
            int j = jq * 64 + jj;
            float pv = ps[il * 257 + j];
            float4 xv = xb4[j * 16 + fq];
            hacc.x = fmaf(pv, xv.x, hacc.x); hacc.y = fmaf(pv, xv.y, hacc.y);
            hacc.z = fmaf(pv, xv.z, hacc.z); hacc.w = fmaf(pv, xv.w, hacc.w);
        }
        hpart[jq][il][fq] = hacc;
    }
    __syncthreads();
    if (t < 64) {
        const int i = t >> 4, f4 = t & 15;
        float4 A = hpart[0][i][f4], Bq = hpart[1][i][f4], C = hpart[2][i][f4], D = hpart[3][i][f4];
        float4 hv;
        hv.x = A.x + Bq.x + C.x + D.x; hv.y = A.y + Bq.y + C.y + D.y;
        hv.z = A.z + Bq.z + C.z + D.z; hv.w = A.w + Bq.w + C.w + D.w;
        hv.x = 1.f / (1.f + __expf(-hv.x)); hv.y = 1.f / (1.f + __expf(-hv.y));
        hv.z = 1.f / (1.f + __expf(-hv.z)); hv.w = 1.f / (1.f + __expf(-hv.w));
        h4s[i][f4] = hv;
    }
    __syncthreads();

    // ---- out[b,i,o] = h[i,:] . fc_w[o,:] + fc_b[o] ; thread = (i, o) ----
    {
        const int oi = wave, o = lane;
        float acc = 0.f;
#pragma unroll
        for (int f4 = 0; f4 < 16; ++f4) {
            float4 hv = h4s[oi][f4];         // broadcast
            float4 wv = fcp[f4 * 64 + o];    // coalesced
            acc = fmaf(hv.x, wv.x, acc); acc = fmaf(hv.y, wv.y, acc);
            acc = fmaf(hv.z, wv.z, acc); acc = fmaf(hv.w, wv.w, acc);
        }
        out[(b * K + i0 + oi) * F + o] = acc + fc_b[o];
    }
}

extern "C" void kernel_launch(void* const* d_in, const int* in_sizes, int n_in,
                              void* d_out, int out_size, void* d_ws, size_t ws_size,
                              hipStream_t stream) {
    const float* x        = (const float*)d_in[0];
    const float* lin_w    = (const float*)d_in[1];
    const float* lin_b    = (const float*)d_in[2];
    const float* a        = (const float*)d_in[3];
    const float* att_bias = (const float*)d_in[4];
    const float* fc_w     = (const float*)d_in[5];
    const float* fc_b     = (const float*)d_in[6];
    float* out = (float*)d_out;

    float* u   = (float*)d_ws;                     // 262144
    float* vT  = u + B * K * E;                    // 262144
    float* c   = vT + B * K * E;                   // 2048
    float* d   = c + B * K;                        // 2048
    float4* wq  = (float4*)(d + B * K);            // 4096 float4
    float4* fcp = wq + 32 * E;                     // 1024 float4

    gat_k0<<<20, 256, 0, stream>>>(lin_w, fc_w, wq, fcp);
    gat_k1<<<B * K / 4, 128, 0, stream>>>(x, wq, lin_b, a, u, vT, c, d);
    gat_k2<<<B * K / 4, 256, 0, stream>>>(x, a, att_bias, fcp, fc_b, u,
                                          (const float4*)vT, c, d, out);
}

// Round 3
// 29.543 us; speedup vs baseline: 1.5730x; 1.1590x over previous
//
#include <hip/hip_runtime.h>
#include <hip/hip_bf16.h>

#define ALPHA 0.2f
constexpr int B = 8, K = 256, F = 64, E = 128;   // E = 2*F

// ---------------------------------------------------------------------------
// Workspace layout (floats):
//   u   [B*K][E]                          262144
//   vT  float4-transposed v: f4-index (b*32+e4)*K + k, component e&3   262144
//   c   [B*K]  = sum_e a_e * v[bk][e]       2048
//   d   [B*K]  = sum_e a_e * u[bk][e]       2048
//   wq  float4 [32][128]: {w1[e][2f],w1[e][2f+1],w2[e][2f],w2[e][2f+1]} 16384
//   fcp float4 [16][64] : {fc_w[o][4f..4f+3]} transposed-packed          4096
// ---------------------------------------------------------------------------

// k0: pack weights for coalesced access (20 blocks x 256)
__global__ __launch_bounds__(256) void gat_k0(
    const float* __restrict__ lin_w, const float* __restrict__ fc_w,
    float4* __restrict__ wq, float4* __restrict__ fcp)
{
    int idx = blockIdx.x * 256 + threadIdx.x;
    if (idx < 32 * E) {                       // 4096: lin_w pack
        int e = idx & (E - 1), f2 = idx >> 7;
        const float* r = lin_w + e * (2 * F) + 2 * f2;
        wq[f2 * E + e] = make_float4(r[0], r[1], r[F], r[F + 1]);
    } else {                                  // 1024: fc_w pack
        int k = idx - 32 * E;
        int f4 = k >> 6, o = k & 63;
        const float* r = fc_w + o * F + f4 * 4;
        fcp[k] = make_float4(r[0], r[1], r[2], r[3]);
    }
}

// k1: 512 blocks x 128 threads; thread e computes rows row0..row0+3.
__global__ __launch_bounds__(128) void gat_k1(
    const float* __restrict__ x, const float4* __restrict__ wq,
    const float* __restrict__ lin_b, const float* __restrict__ a,
    float* __restrict__ u, float* __restrict__ vT,
    float* __restrict__ c, float* __restrict__ d)
{
    const int e = threadIdx.x;               // 0..127
    const int row0 = blockIdx.x * 4;

    __shared__ float xs[4 * F];              // 4 rows of x
    xs[e] = x[row0 * F + e];
    xs[e + 128] = x[row0 * F + e + 128];
    __syncthreads();

    float acc1[4] = {0, 0, 0, 0}, acc2[4] = {0, 0, 0, 0};
#pragma unroll
    for (int f2 = 0; f2 < 32; ++f2) {
        float4 w = wq[f2 * E + e];           // coalesced 16B/lane
#pragma unroll
        for (int r = 0; r < 4; ++r) {
            float xa = xs[r * F + 2 * f2], xb = xs[r * F + 2 * f2 + 1];
            acc1[r] = fmaf(w.x, xa, fmaf(w.y, xb, acc1[r]));
            acc2[r] = fmaf(w.z, xa, fmaf(w.w, xb, acc2[r]));
        }
    }

    const float bb = lin_b[e], av = a[e];
    float vals[8];
#pragma unroll
    for (int r = 0; r < 4; ++r) {
        int bk = row0 + r;
        float uu = acc1[r] + bb;
        u[bk * E + e] = uu;
        int b = bk >> 8, k = bk & 255;
        vT[(((b * 32) + (e >> 2)) * K + k) * 4 + (e & 3)] = acc2[r];
        vals[r]     = av * acc2[r];          // c partial
        vals[4 + r] = av * uu;               // d partial
    }
#pragma unroll
    for (int off = 32; off; off >>= 1)
#pragma unroll
        for (int q = 0; q < 8; ++q) vals[q] += __shfl_xor(vals[q], off);

    __shared__ float red[2][8];
    const int wave = e >> 6, lane = e & 63;
    if (lane == 0)
#pragma unroll
        for (int q = 0; q < 8; ++q) red[wave][q] = vals[q];
    __syncthreads();
    if (e < 4)      c[row0 + e] = red[0][e] + red[1][e];
    else if (e < 8) d[row0 + e - 4] = red[0][e] + red[1][e];
}

// k2: 512 blocks x 256 threads; block = (b, 4 consecutive i rows); thread t = j.
// u-tile and 0.4*a staged in LDS (wave-uniform broadcast reads); only the
// streaming vT load touches global per inner iteration.
__global__ __launch_bounds__(256, 2) void gat_k2(
    const float* __restrict__ x, const float* __restrict__ a,
    const float* __restrict__ att_bias, const float4* __restrict__ fcp,
    const float* __restrict__ fc_b, const float* __restrict__ u,
    const float4* __restrict__ vT4, const float* __restrict__ c,
    const float* __restrict__ d, float* __restrict__ out)
{
    const int blk = blockIdx.x;
    const int b = blk >> 6;
    const int i0 = (blk & 63) * 4;
    const int t = threadIdx.x;               // j
    const int wave = t >> 6, lane = t & 63;

    __shared__ float us[4 * E];              // u rows i0..i0+3
    __shared__ float aas[E];                 // 0.4 * a
    __shared__ float ps[4 * 257];            // padded
    __shared__ float4 hpart[4][4][16];
    __shared__ float4 h4s[4][16];
    __shared__ float redm[4][4], reds[4][4];

    // ---- preamble: stage reused data, issue latency-bound loads early ----
    {
        const float* usrc = u + (size_t)(b * K + i0) * E;   // 512 consecutive
        us[t]       = usrc[t];
        us[t + 256] = usrc[t + 256];
        if (t < E) aas[t] = 0.4f * a[t];
    }
    const float cj = c[b * K + t];
    const float d0 = d[b * K + i0],     d1 = d[b * K + i0 + 1];
    const float d2 = d[b * K + i0 + 2], d3 = d[b * K + i0 + 3];
    const float ab0 = att_bias[(i0 + 0) * K + t];
    const float ab1 = att_bias[(i0 + 1) * K + t];
    const float ab2 = att_bias[(i0 + 2) * K + t];
    const float ab3 = att_bias[(i0 + 3) * K + t];
    __syncthreads();

    // ---- e-loop: ej_abs[i] = sum_e (0.4 a_e) * |u_ie + v_je| ----
    const float4* v4 = vT4 + (size_t)b * 32 * K + t;
    float ej0 = 0.f, ej1 = 0.f, ej2 = 0.f, ej3 = 0.f;
#pragma unroll 4
    for (int e4 = 0; e4 < 32; ++e4) {
        float4 v  = v4[e4 * K];              // coalesced 16B/lane (only global)
        float4 aa = *(const float4*)&aas[e4 * 4];
        float4 u0 = *(const float4*)&us[0 * E + e4 * 4];
        float4 u1 = *(const float4*)&us[1 * E + e4 * 4];
        float4 u2 = *(const float4*)&us[2 * E + e4 * 4];
        float4 u3 = *(const float4*)&us[3 * E + e4 * 4];
        ej0 = fmaf(aa.x, fabsf(u0.x + v.x), ej0); ej0 = fmaf(aa.y, fabsf(u0.y + v.y), ej0);
        ej0 = fmaf(aa.z, fabsf(u0.z + v.z), ej0); ej0 = fmaf(aa.w, fabsf(u0.w + v.w), ej0);
        ej1 = fmaf(aa.x, fabsf(u1.x + v.x), ej1); ej1 = fmaf(aa.y, fabsf(u1.y + v.y), ej1);
        ej1 = fmaf(aa.z, fabsf(u1.z + v.z), ej1); ej1 = fmaf(aa.w, fabsf(u1.w + v.w), ej1);
        ej2 = fmaf(aa.x, fabsf(u2.x + v.x), ej2); ej2 = fmaf(aa.y, fabsf(u2.y + v.y), ej2);
        ej2 = fmaf(aa.z, fabsf(u2.z + v.z), ej2); ej2 = fmaf(aa.w, fabsf(u2.w + v.w), ej2);
        ej3 = fmaf(aa.x, fabsf(u3.x + v.x), ej3); ej3 = fmaf(aa.y, fabsf(u3.y + v.y), ej3);
        ej3 = fmaf(aa.z, fabsf(u3.z + v.z), ej3); ej3 = fmaf(aa.w, fabsf(u3.w + v.w), ej3);
    }
    // e_ij = 0.6(d_i + c_j) + 0.4*ej_abs + att_bias  (lrelu z = 0.6 z + 0.4|z|)
    float e0 = fmaf(0.6f, d0 + cj, ej0) + ab0;
    float e1 = fmaf(0.6f, d1 + cj, ej1) + ab1;
    float e2 = fmaf(0.6f, d2 + cj, ej2) + ab2;
    float e3 = fmaf(0.6f, d3 + cj, ej3) + ab3;

    // ---- softmax over j (4 rows) ----
    float m0 = e0, m1 = e1, m2 = e2, m3 = e3;
#pragma unroll
    for (int off = 32; off; off >>= 1) {
        m0 = fmaxf(m0, __shfl_xor(m0, off)); m1 = fmaxf(m1, __shfl_xor(m1, off));
        m2 = fmaxf(m2, __shfl_xor(m2, off)); m3 = fmaxf(m3, __shfl_xor(m3, off));
    }
    if (lane == 0) { redm[wave][0] = m0; redm[wave][1] = m1; redm[wave][2] = m2; redm[wave][3] = m3; }
    __syncthreads();
    m0 = fmaxf(fmaxf(redm[0][0], redm[1][0]), fmaxf(redm[2][0], redm[3][0]));
    m1 = fmaxf(fmaxf(redm[0][1], redm[1][1]), fmaxf(redm[2][1], redm[3][1]));
    m2 = fmaxf(fmaxf(redm[0][2], redm[1][2]), fmaxf(redm[2][2], redm[3][2]));
    m3 = fmaxf(fmaxf(redm[0][3], redm[1][3]), fmaxf(redm[2][3], redm[3][3]));
    float x0 = __expf(e0 - m0), x1 = __expf(e1 - m1), x2 = __expf(e2 - m2), x3 = __expf(e3 - m3);
    float s0 = x0, s1 = x1, s2 = x2, s3 = x3;
#pragma unroll
    for (int off = 32; off; off >>= 1) {
        s0 += __shfl_xor(s0, off); s1 += __shfl_xor(s1, off);
        s2 += __shfl_xor(s2, off); s3 += __shfl_xor(s3, off);
    }
    if (lane == 0) { reds[wave][0] = s0; reds[wave][1] = s1; reds[wave][2] = s2; reds[wave][3] = s3; }
    __syncthreads();
    s0 = reds[0][0] + reds[1][0] + reds[2][0] + reds[3][0];
    s1 = reds[0][1] + reds[1][1] + reds[2][1] + reds[3][1];
    s2 = reds[0][2] + reds[1][2] + reds[2][2] + reds[3][2];
    s3 = reds[0][3] + reds[1][3] + reds[2][3] + reds[3][3];
    ps[0 * 257 + t] = x0 / s0;
    ps[1 * 257 + t] = x1 / s1;
    ps[2 * 257 + t] = x2 / s2;
    ps[3 * 257 + t] = x3 / s3;
    __syncthreads();

    // ---- h[i,f] = sigmoid(sum_j p[i,j] x[b,j,f]) ; thread = (jq, il, fq) ----
    {
        const int jq = wave, il = (t >> 4) & 3, fq = t & 15;
        const float4* xb4 = (const float4*)x + (size_t)b * K * 16;
        float4 hacc = make_float4(0.f, 0.f, 0.f, 0.f);
#pragma unroll 8
        for (int jj = 0; jj < 64; ++jj) {
            int j = jq * 64 + jj;
            float pv = ps[il * 257 + j];
            float4 xv = xb4[j * 16 + fq];
            hacc.x = fmaf(pv, xv.x, hacc.x); hacc.y = fmaf(pv, xv.y, hacc.y);
            hacc.z = fmaf(pv, xv.z, hacc.z); hacc.w = fmaf(pv, xv.w, hacc.w);
        }
        hpart[jq][il][fq] = hacc;
    }
    __syncthreads();
    if (t < 64) {
        const int i = t >> 4, f4 = t & 15;
        float4 A = hpart[0][i][f4], Bq = hpart[1][i][f4], C = hpart[2][i][f4], D = hpart[3][i][f4];
        float4 hv;
        hv.x = A.x + Bq.x + C.x + D.x; hv.y = A.y + Bq.y + C.y + D.y;
        hv.z = A.z + Bq.z + C.z + D.z; hv.w = A.w + Bq.w + C.w + D.w;
        hv.x = 1.f / (1.f + __expf(-hv.x)); hv.y = 1.f / (1.f + __expf(-hv.y));
        hv.z = 1.f / (1.f + __expf(-hv.z)); hv.w = 1.f / (1.f + __expf(-hv.w));
        h4s[i][f4] = hv;
    }
    __syncthreads();

    // ---- out[b,i,o] = h[i,:] . fc_w[o,:] + fc_b[o] ; thread = (i, o) ----
    {
        const int oi = wave, o = lane;
        float acc = 0.f;
#pragma unroll
        for (int f4 = 0; f4 < 16; ++f4) {
            float4 hv = h4s[oi][f4];         // broadcast
            float4 wv = fcp[f4 * 64 + o];    // coalesced
            acc = fmaf(hv.x, wv.x, acc); acc = fmaf(hv.y, wv.y, acc);
            acc = fmaf(hv.z, wv.z, acc); acc = fmaf(hv.w, wv.w, acc);
        }
        out[(b * K + i0 + oi) * F + o] = acc + fc_b[o];
    }
}

extern "C" void kernel_launch(void* const* d_in, const int* in_sizes, int n_in,
                              void* d_out, int out_size, void* d_ws, size_t ws_size,
                              hipStream_t stream) {
    const float* x        = (const float*)d_in[0];
    const float* lin_w    = (const float*)d_in[1];
    const float* lin_b    = (const float*)d_in[2];
    const float* a        = (const float*)d_in[3];
    const float* att_bias = (const float*)d_in[4];
    const float* fc_w     = (const float*)d_in[5];
    const float* fc_b     = (const float*)d_in[6];
    float* out = (float*)d_out;

    float* u   = (float*)d_ws;                     // 262144
    float* vT  = u + B * K * E;                    // 262144
    float* c   = vT + B * K * E;                   // 2048
    float* d   = c + B * K;                        // 2048
    float4* wq  = (float4*)(d + B * K);            // 4096 float4
    float4* fcp = wq + 32 * E;                     // 1024 float4

    gat_k0<<<20, 256, 0, stream>>>(lin_w, fc_w, wq, fcp);
    gat_k1<<<B * K / 4, 128, 0, stream>>>(x, wq, lin_b, a, u, vT, c, d);
    gat_k2<<<B * K / 4, 256, 0, stream>>>(x, a, att_bias, fcp, fc_b, u,
                                          (const float4*)vT, c, d, out);
}